// Round 13
// baseline (189.952 us; speedup 1.0000x reference)
//
#include <hip/hip_runtime.h>
#include <hip/hip_bf16.h>

// NAM_89739046683406: per-feature tiny MLP (B=32768, F=128, H=64)
// logit(b) = bias + sum_f [ relu(relu(x[b,f]*w1[f]+b1[f]) @ w2[f] + b2[f]) . w3[f] + b3[f] ]
// out = [1-sigmoid, sigmoid]
//
// R13 = R12 f-outer structure + latency fixes: grid 2048 (wave = 1 f x 512
// rows, 8 chunks), LB(256,4) -> 4 blocks/CU resident; software prefetch of
// next chunk's x; 4 direct 16-line x loads instead of 1 gather + 4 bpermute.
// All per-f weights stay in registers for the wave's lifetime.

#define B_SZ 32768
#define F_SZ 128
#define H_SZ 64

typedef short short8 __attribute__((ext_vector_type(8)));   // bf16 x8
typedef float floatx4 __attribute__((ext_vector_type(4)));  // fp32 x4 acc

// round-half-up bf16 pair-pack (proven form)
__device__ __forceinline__ unsigned pkbf(float lo, float hi) {
    unsigned ua = __float_as_uint(lo) + 0x8000u;
    unsigned ub = __float_as_uint(hi) + 0x8000u;
    return (ua >> 16) | (ub & 0xFFFF0000u);
}

// ws layout (bytes): [0, 1MB) w2bf fragment table; [1MB, 1MB+128KB) logit
#define WS_LOG_SHORTS 524288

// ---- prep: blocks [0,256) pack w2 -> A-fragment order (grid-strided, uniform)
//      blocks [256,288) zero the logit buffer
// fragment layout: per f, unit idx = c*64+lane (c = gt*2+ks):
//   value = w2[f][k=(c&1)*32+(lane>>4)*8+j][g=(c>>1)*16+(lane&15)], j=0..7
__global__ __launch_bounds__(256)
void nam_prep(const float* __restrict__ w2, unsigned short* __restrict__ ws)
{
    const int bx = blockIdx.x, tid = threadIdx.x;
    if (bx < 256) {
        int unit = bx * 256 + tid;        // 0..65535
        int f    = unit >> 9;             // 0..127
        int idx  = unit & 511;
        int c    = idx >> 6;
        int lane = idx & 63;
        int g    = (c >> 1) * 16 + (lane & 15);
        int k0   = (c & 1) * 32 + (lane >> 4) * 8;
        const float* w2f = w2 + (size_t)f * 4096;
        unsigned o0 = pkbf(w2f[(k0 + 0) * 64 + g], w2f[(k0 + 1) * 64 + g]);
        unsigned o1 = pkbf(w2f[(k0 + 2) * 64 + g], w2f[(k0 + 3) * 64 + g]);
        unsigned o2 = pkbf(w2f[(k0 + 4) * 64 + g], w2f[(k0 + 5) * 64 + g]);
        unsigned o3 = pkbf(w2f[(k0 + 6) * 64 + g], w2f[(k0 + 7) * 64 + g]);
        *(uint4*)((unsigned*)ws + ((size_t)f * 512 + idx) * 4) =
            make_uint4(o0, o1, o2, o3);
    } else {
        float4* logit4 = (float4*)(ws + WS_LOG_SHORTS);
        logit4[(bx - 256) * 256 + tid] = make_float4(0.f, 0.f, 0.f, 0.f);
    }
}

// ---- main: block = 4 waves; wave wv owns feature f = (bx>>6)*4+wv,
//      rows [rg*512, rg*512+512), rg = bx&63. 8 chunks of 64 rows.
__global__ __launch_bounds__(256, 4)
void nam_main(const float* __restrict__ x,
              const float* __restrict__ w1, const float* __restrict__ b1,
              const float* __restrict__ b2, const float* __restrict__ w3,
              const float* __restrict__ b3,
              const unsigned short* __restrict__ ws,
              float* __restrict__ logit)
{
    __shared__ float partial[4][512];    // 8KB

    const int tid  = threadIdx.x;
    const int lane = tid & 63;
    const int wv   = tid >> 6;           // 0..3
    const int l15  = lane & 15;
    const int quad = lane >> 4;
    const int rg   = blockIdx.x & 63;
    const int gf   = blockIdx.x >> 6;    // 0..31
    const int f    = gf * 4 + wv;
    const int rb   = rg * 512;

    // ---- per-wave resident tables ----
    // w2 A-fragments (8 x 16B coalesced loads, L2-hot)
    const short8* wp = (const short8*)ws + (size_t)f * 512 + lane;
    short8 wfrag[4][2];
    #pragma unroll
    for (int gt = 0; gt < 4; ++gt)
        #pragma unroll
        for (int ks = 0; ks < 2; ++ks)
            wfrag[gt][ks] = wp[(gt * 2 + ks) * 64];

    // w1/b1 fp32: element k = ks*32 + quad*8 + j
    float wk[2][8], bk[2][8];
    #pragma unroll
    for (int ks = 0; ks < 2; ++ks) {
        const float4* wq = (const float4*)(w1 + f * 64 + ks * 32 + quad * 8);
        const float4* bq = (const float4*)(b1 + f * 64 + ks * 32 + quad * 8);
        *(float4*)&wk[ks][0] = wq[0]; *(float4*)&wk[ks][4] = wq[1];
        *(float4*)&bk[ks][0] = bq[0]; *(float4*)&bk[ks][4] = bq[1];
    }

    // b2/w3 fp32: element g = gt*16 + quad*4 + i
    float b2f[4][4], w3f[4][4];
    #pragma unroll
    for (int gt = 0; gt < 4; ++gt) {
        *(float4*)&b2f[gt][0] = *(const float4*)(b2 + f * 64 + gt * 16 + quad * 4);
        *(float4*)&w3f[gt][0] = *(const float4*)(w3 + f * 64 + gt * 16 + quad * 4);
    }
    const float b3f = b3[f];

    // per-lane x pointer: row rb + l15 (+ chunk/bt offsets), col f.
    // All 4 quads read the same 16 rows -> 16-line coalesced broadcast loads.
    const float* xp = x + (size_t)(rb + l15) * F_SZ + f;

    float xf[4], xn[4];
    #pragma unroll
    for (int bt = 0; bt < 4; ++bt)
        xf[bt] = xp[(size_t)(bt * 16) * F_SZ];

    // ---- 8 chunks of 64 rows, software-pipelined x loads ----
    #pragma unroll 1
    for (int c = 0; c < 8; ++c) {
        if (c < 7) {
            #pragma unroll
            for (int bt = 0; bt < 4; ++bt)
                xn[bt] = xp[(size_t)((c + 1) * 64 + bt * 16) * F_SZ];
        }

        // h1 B-fragments: B[k=quad*8+j][n=bt*16+l15]
        short8 hfrag[4][2];
        #pragma unroll
        for (int ks = 0; ks < 2; ++ks)
            #pragma unroll
            for (int bt = 0; bt < 4; ++bt) {
                union { short8 s8; __hip_bfloat162 h2[4]; } o;
                #pragma unroll
                for (int t = 0; t < 4; ++t) {
                    float h0 = fmaxf(fmaf(xf[bt], wk[ks][2 * t],     bk[ks][2 * t]),     0.0f);
                    float h1 = fmaxf(fmaf(xf[bt], wk[ks][2 * t + 1], bk[ks][2 * t + 1]), 0.0f);
                    o.h2[t] = __float22bfloat162_rn(make_float2(h0, h1));
                }
                hfrag[bt][ks] = o.s8;
            }

        // MFMA + epilogue; D layout: g = gt*16 + quad*4 + i, n = bt*16 + l15
        float t[4] = {0.0f, 0.0f, 0.0f, 0.0f};
        #pragma unroll
        for (int gt = 0; gt < 4; ++gt)
            #pragma unroll
            for (int bt = 0; bt < 4; ++bt) {
                floatx4 acc = {b2f[gt][0], b2f[gt][1], b2f[gt][2], b2f[gt][3]};
                acc = __builtin_amdgcn_mfma_f32_16x16x32_bf16(
                    wfrag[gt][0], hfrag[bt][0], acc, 0, 0, 0);
                acc = __builtin_amdgcn_mfma_f32_16x16x32_bf16(
                    wfrag[gt][1], hfrag[bt][1], acc, 0, 0, 0);
                #pragma unroll
                for (int i = 0; i < 4; ++i)
                    t[bt] = fmaf(fmaxf(acc[i], 0.0f), w3f[gt][i], t[bt]);
            }

        // quad-reduce (row = bt*16 + l15), publish chunk rows
        #pragma unroll
        for (int bt = 0; bt < 4; ++bt) {
            t[bt] += __shfl_xor(t[bt], 16, 64);
            t[bt] += __shfl_xor(t[bt], 32, 64);
        }
        if (quad == 0) {
            #pragma unroll
            for (int bt = 0; bt < 4; ++bt)
                partial[wv][c * 64 + bt * 16 + l15] = t[bt] + b3f;
        }

        #pragma unroll
        for (int bt = 0; bt < 4; ++bt) xf[bt] = xn[bt];
    }

    __syncthreads();

    // block reduce over the 4 features, 1 atomic per row
    #pragma unroll
    for (int k = 0; k < 2; ++k) {
        int row = k * 256 + tid;
        float p = partial[0][row] + partial[1][row]
                + partial[2][row] + partial[3][row];
        atomicAdd(&logit[rb + row], p);
    }
}

__global__ __launch_bounds__(256)
void nam_final(const float* __restrict__ logit, const float* __restrict__ bias,
               float* __restrict__ out)
{
    const float bs = bias[0];
    #pragma unroll
    for (int k = 0; k < 4; ++k) {
        int b = blockIdx.x * 1024 + k * 256 + threadIdx.x;
        float s = logit[b] + bs;
        float p = 1.0f / (1.0f + __expf(-s));
        ((float2*)out)[b] = make_float2(1.0f - p, p);
    }
}

extern "C" void kernel_launch(void* const* d_in, const int* in_sizes, int n_in,
                              void* d_out, int out_size, void* d_ws, size_t ws_size,
                              hipStream_t stream)
{
    const float* x    = (const float*)d_in[0];
    const float* w1   = (const float*)d_in[1];
    const float* b1   = (const float*)d_in[2];
    const float* w2   = (const float*)d_in[3];
    const float* b2   = (const float*)d_in[4];
    const float* w3   = (const float*)d_in[5];
    const float* b3   = (const float*)d_in[6];
    const float* bias = (const float*)d_in[7];
    float* out = (float*)d_out;

    unsigned short* ws = (unsigned short*)d_ws;
    float* logit = (float*)(ws + WS_LOG_SHORTS);

    nam_prep<<<dim3(288), dim3(256), 0, stream>>>(w2, ws);
    nam_main<<<dim3(2048), dim3(256), 0, stream>>>(
        x, w1, b1, b2, w3, b3, ws, logit);
    nam_final<<<dim3(B_SZ / 1024), dim3(256), 0, stream>>>(logit, bias, out);
}

// Round 14
// 153.277 us; speedup vs baseline: 1.2393x; 1.2393x over previous
//
#include <hip/hip_runtime.h>
#include <hip/hip_bf16.h>

// NAM_89739046683406: per-feature tiny MLP (B=32768, F=128, H=64)
// logit(b) = bias + sum_f [ relu(relu(x[b,f]*w1[f]+b1[f]) @ w2[f] + b2[f]) . w3[f] + b3[f] ]
// out = [1-sigmoid, sigmoid]
//
// R14 = R12 (proven memory layout: FETCH 12.8MB / WRITE 4MB) + two fixes:
//   (1) __launch_bounds__(256,4): grid 1024 = exactly 4 blocks/CU -> all
//       resident (R12's LB(256,3) stranded 25% of blocks in a serial tail).
//   (2) software prefetch of next chunk's x (R13-proven construct) to hide
//       the dependent VMEM latency at each chunk head.
// Everything else (grid mapping rg=bx&31, gather+shuffle x loads, LDS
// partials, 1M spread atomics, prep/final kernels) is byte-identical to R12.
// R13's lesson: do NOT touch the block<->rows/features mapping — L2 sharing
// of x lines and logit lines depends on it (R13: WRITE 4->110MB).

#define B_SZ 32768
#define F_SZ 128
#define H_SZ 64

typedef short short8 __attribute__((ext_vector_type(8)));   // bf16 x8
typedef float floatx4 __attribute__((ext_vector_type(4)));  // fp32 x4 acc

// round-half-up bf16 pair-pack (proven form)
__device__ __forceinline__ unsigned pkbf(float lo, float hi) {
    unsigned ua = __float_as_uint(lo) + 0x8000u;
    unsigned ub = __float_as_uint(hi) + 0x8000u;
    return (ua >> 16) | (ub & 0xFFFF0000u);
}

// ws layout (bytes): [0, 1MB) w2bf fragment table; [1MB, 1MB+128KB) logit
#define WS_LOG_SHORTS 524288

// ---- prep: blocks [0,256) pack w2 -> A-fragment order (grid-strided, uniform)
//      blocks [256,288) zero the logit buffer
// fragment layout: per f, unit idx = c*64+lane (c = gt*2+ks):
//   value = w2[f][k=(c&1)*32+(lane>>4)*8+j][g=(c>>1)*16+(lane&15)], j=0..7
__global__ __launch_bounds__(256)
void nam_prep(const float* __restrict__ w2, unsigned short* __restrict__ ws)
{
    const int bx = blockIdx.x, tid = threadIdx.x;
    if (bx < 256) {
        int unit = bx * 256 + tid;        // 0..65535
        int f    = unit >> 9;             // 0..127
        int idx  = unit & 511;
        int c    = idx >> 6;
        int lane = idx & 63;
        int g    = (c >> 1) * 16 + (lane & 15);
        int k0   = (c & 1) * 32 + (lane >> 4) * 8;
        const float* w2f = w2 + (size_t)f * 4096;
        unsigned o0 = pkbf(w2f[(k0 + 0) * 64 + g], w2f[(k0 + 1) * 64 + g]);
        unsigned o1 = pkbf(w2f[(k0 + 2) * 64 + g], w2f[(k0 + 3) * 64 + g]);
        unsigned o2 = pkbf(w2f[(k0 + 4) * 64 + g], w2f[(k0 + 5) * 64 + g]);
        unsigned o3 = pkbf(w2f[(k0 + 6) * 64 + g], w2f[(k0 + 7) * 64 + g]);
        *(uint4*)((unsigned*)ws + ((size_t)f * 512 + idx) * 4) =
            make_uint4(o0, o1, o2, o3);
    } else {
        float4* logit4 = (float4*)(ws + WS_LOG_SHORTS);
        logit4[(bx - 256) * 256 + tid] = make_float4(0.f, 0.f, 0.f, 0.f);
    }
}

// ---- main: block = 4 waves; wave wv owns feature f = (bx>>5)*4+wv,
//      rows [rg*1024, rg*1024+1024), rg = bx&31. 16 chunks of 64 rows.
__global__ __launch_bounds__(256, 4)
void nam_main(const float* __restrict__ x,
              const float* __restrict__ w1, const float* __restrict__ b1,
              const float* __restrict__ b2, const float* __restrict__ w3,
              const float* __restrict__ b3,
              const unsigned short* __restrict__ ws,
              float* __restrict__ logit)
{
    __shared__ float partial[4][1024];   // 16KB

    const int tid  = threadIdx.x;
    const int lane = tid & 63;
    const int wv   = tid >> 6;           // 0..3
    const int l15  = lane & 15;
    const int quad = lane >> 4;
    const int rg   = blockIdx.x & 31;
    const int gf   = blockIdx.x >> 5;    // 0..31
    const int f    = gf * 4 + wv;
    const int rb   = rg * 1024;

    // ---- per-wave resident tables ----
    // w2 A-fragments (8 x 16B coalesced loads)
    const short8* wp = (const short8*)ws + (size_t)f * 512 + lane;
    short8 wfrag[4][2];
    #pragma unroll
    for (int gt = 0; gt < 4; ++gt)
        #pragma unroll
        for (int ks = 0; ks < 2; ++ks)
            wfrag[gt][ks] = wp[(gt * 2 + ks) * 64];

    // w1/b1 fp32: element k = ks*32 + quad*8 + j
    float wk[2][8], bk[2][8];
    #pragma unroll
    for (int ks = 0; ks < 2; ++ks) {
        const float4* wq = (const float4*)(w1 + f * 64 + ks * 32 + quad * 8);
        const float4* bq = (const float4*)(b1 + f * 64 + ks * 32 + quad * 8);
        *(float4*)&wk[ks][0] = wq[0]; *(float4*)&wk[ks][4] = wq[1];
        *(float4*)&bk[ks][0] = bq[0]; *(float4*)&bk[ks][4] = bq[1];
    }

    // b2/w3 fp32: element g = gt*16 + quad*4 + i
    float b2f[4][4], w3f[4][4];
    #pragma unroll
    for (int gt = 0; gt < 4; ++gt) {
        *(float4*)&b2f[gt][0] = *(const float4*)(b2 + f * 64 + gt * 16 + quad * 4);
        *(float4*)&w3f[gt][0] = *(const float4*)(w3 + f * 64 + gt * 16 + quad * 4);
    }
    const float b3f = b3[f];

    // ---- 16 chunks of 64 rows, software-pipelined x gather ----
    float xv = x[(size_t)(rb + lane) * F_SZ + f];   // chunk 0

    #pragma unroll 1
    for (int c = 0; c < 16; ++c) {
        float xvn;
        if (c < 15)
            xvn = x[(size_t)(rb + (c + 1) * 64 + lane) * F_SZ + f];

        float xf[4];
        #pragma unroll
        for (int bt = 0; bt < 4; ++bt)
            xf[bt] = __shfl(xv, bt * 16 + l15, 64);

        // h1 B-fragments: B[k=quad*8+j][n=bt*16+l15]
        short8 hfrag[4][2];
        #pragma unroll
        for (int ks = 0; ks < 2; ++ks)
            #pragma unroll
            for (int bt = 0; bt < 4; ++bt) {
                union { short8 s8; __hip_bfloat162 h2[4]; } o;
                #pragma unroll
                for (int t = 0; t < 4; ++t) {
                    float h0 = fmaxf(fmaf(xf[bt], wk[ks][2 * t],     bk[ks][2 * t]),     0.0f);
                    float h1 = fmaxf(fmaf(xf[bt], wk[ks][2 * t + 1], bk[ks][2 * t + 1]), 0.0f);
                    o.h2[t] = __float22bfloat162_rn(make_float2(h0, h1));
                }
                hfrag[bt][ks] = o.s8;
            }

        // MFMA + epilogue; D layout: g = gt*16 + quad*4 + i, n = bt*16 + l15
        float t[4] = {0.0f, 0.0f, 0.0f, 0.0f};
        #pragma unroll
        for (int gt = 0; gt < 4; ++gt)
            #pragma unroll
            for (int bt = 0; bt < 4; ++bt) {
                floatx4 acc = {b2f[gt][0], b2f[gt][1], b2f[gt][2], b2f[gt][3]};
                acc = __builtin_amdgcn_mfma_f32_16x16x32_bf16(
                    wfrag[gt][0], hfrag[bt][0], acc, 0, 0, 0);
                acc = __builtin_amdgcn_mfma_f32_16x16x32_bf16(
                    wfrag[gt][1], hfrag[bt][1], acc, 0, 0, 0);
                #pragma unroll
                for (int i = 0; i < 4; ++i)
                    t[bt] = fmaf(fmaxf(acc[i], 0.0f), w3f[gt][i], t[bt]);
            }

        // quad-reduce (row = bt*16 + l15), publish per-chunk rows
        #pragma unroll
        for (int bt = 0; bt < 4; ++bt) {
            t[bt] += __shfl_xor(t[bt], 16, 64);
            t[bt] += __shfl_xor(t[bt], 32, 64);
        }
        if (quad == 0) {
            #pragma unroll
            for (int bt = 0; bt < 4; ++bt)
                partial[wv][c * 64 + bt * 16 + l15] = t[bt] + b3f;
        }

        xv = xvn;
    }

    __syncthreads();

    // block reduce over the 4 features, 1 atomic per row
    #pragma unroll
    for (int k = 0; k < 4; ++k) {
        int row = k * 256 + tid;
        float p = partial[0][row] + partial[1][row]
                + partial[2][row] + partial[3][row];
        atomicAdd(&logit[rb + row], p);
    }
}

__global__ __launch_bounds__(256)
void nam_final(const float* __restrict__ logit, const float* __restrict__ bias,
               float* __restrict__ out)
{
    const float bs = bias[0];
    #pragma unroll
    for (int k = 0; k < 4; ++k) {
        int b = blockIdx.x * 1024 + k * 256 + threadIdx.x;
        float s = logit[b] + bs;
        float p = 1.0f / (1.0f + __expf(-s));
        ((float2*)out)[b] = make_float2(1.0f - p, p);
    }
}

extern "C" void kernel_launch(void* const* d_in, const int* in_sizes, int n_in,
                              void* d_out, int out_size, void* d_ws, size_t ws_size,
                              hipStream_t stream)
{
    const float* x    = (const float*)d_in[0];
    const float* w1   = (const float*)d_in[1];
    const float* b1   = (const float*)d_in[2];
    const float* w2   = (const float*)d_in[3];
    const float* b2   = (const float*)d_in[4];
    const float* w3   = (const float*)d_in[5];
    const float* b3   = (const float*)d_in[6];
    const float* bias = (const float*)d_in[7];
    float* out = (float*)d_out;

    unsigned short* ws = (unsigned short*)d_ws;
    float* logit = (float*)(ws + WS_LOG_SHORTS);

    nam_prep<<<dim3(288), dim3(256), 0, stream>>>(w2, ws);
    nam_main<<<dim3(1024), dim3(256), 0, stream>>>(
        x, w1, b1, b2, w3, b3, ws, logit);
    nam_final<<<dim3(B_SZ / 1024), dim3(256), 0, stream>>>(logit, bias, out);
}

// Round 15
// 148.616 us; speedup vs baseline: 1.2781x; 1.0314x over previous
//
#include <hip/hip_runtime.h>
#include <hip/hip_bf16.h>

// NAM_89739046683406: per-feature tiny MLP (B=32768, F=128, H=64)
// logit(b) = bias + sum_f [ relu(relu(x[b,f]*w1[f]+b1[f]) @ w2[f] + b2[f]) . w3[f] + b3[f] ]
// out = [1-sigmoid, sigmoid]
//
// R15 = R12/R14 f-outer structure with the cross-block atomic RMW removed:
// each block writes its block-reduced 1024-row partial as a plain coalesced
// store to part[gf][rows] (one writer per line, streaming). Final kernel sums
// the 32 gf-partials + bias + sigmoid. LB(256,4) + x prefetch retained (with
// atomics gone, co-residency hides x latency instead of thrashing lines).
// R14 evidence: atomics @ 4 blk/CU -> WRITE 43.8MB (line ping-pong). Predict
// WRITE ~4.5MB here.

#define B_SZ 32768
#define F_SZ 128
#define H_SZ 64

typedef short short8 __attribute__((ext_vector_type(8)));   // bf16 x8
typedef float floatx4 __attribute__((ext_vector_type(4)));  // fp32 x4 acc

// round-half-up bf16 pair-pack (proven form)
__device__ __forceinline__ unsigned pkbf(float lo, float hi) {
    unsigned ua = __float_as_uint(lo) + 0x8000u;
    unsigned ub = __float_as_uint(hi) + 0x8000u;
    return (ua >> 16) | (ub & 0xFFFF0000u);
}

// ws layout (bytes): [0, 1MB) w2bf fragment table; [1MB, 5MB) part[32][32768]
#define WS_PART_SHORTS 524288

// ---- prep: pack w2 -> A-fragment order (grid-strided, uniform, 256 blocks)
// fragment layout: per f, unit idx = c*64+lane (c = gt*2+ks):
//   value = w2[f][k=(c&1)*32+(lane>>4)*8+j][g=(c>>1)*16+(lane&15)], j=0..7
__global__ __launch_bounds__(256)
void nam_prep(const float* __restrict__ w2, unsigned short* __restrict__ ws)
{
    int unit = blockIdx.x * 256 + threadIdx.x;   // 0..65535
    int f    = unit >> 9;             // 0..127
    int idx  = unit & 511;
    int c    = idx >> 6;
    int lane = idx & 63;
    int g    = (c >> 1) * 16 + (lane & 15);
    int k0   = (c & 1) * 32 + (lane >> 4) * 8;
    const float* w2f = w2 + (size_t)f * 4096;
    unsigned o0 = pkbf(w2f[(k0 + 0) * 64 + g], w2f[(k0 + 1) * 64 + g]);
    unsigned o1 = pkbf(w2f[(k0 + 2) * 64 + g], w2f[(k0 + 3) * 64 + g]);
    unsigned o2 = pkbf(w2f[(k0 + 4) * 64 + g], w2f[(k0 + 5) * 64 + g]);
    unsigned o3 = pkbf(w2f[(k0 + 6) * 64 + g], w2f[(k0 + 7) * 64 + g]);
    *(uint4*)((unsigned*)ws + ((size_t)f * 512 + idx) * 4) =
        make_uint4(o0, o1, o2, o3);
}

// ---- main: block = 4 waves; wave wv owns feature f = (bx>>5)*4+wv,
//      rows [rg*1024, rg*1024+1024), rg = bx&31. 16 chunks of 64 rows.
//      Output: part[gf][rb..rb+1024) plain store (sole writer).
__global__ __launch_bounds__(256, 4)
void nam_main(const float* __restrict__ x,
              const float* __restrict__ w1, const float* __restrict__ b1,
              const float* __restrict__ b2, const float* __restrict__ w3,
              const float* __restrict__ b3,
              const unsigned short* __restrict__ ws,
              float* __restrict__ part)
{
    __shared__ float partial[4][1024];   // 16KB

    const int tid  = threadIdx.x;
    const int lane = tid & 63;
    const int wv   = tid >> 6;           // 0..3
    const int l15  = lane & 15;
    const int quad = lane >> 4;
    const int rg   = blockIdx.x & 31;
    const int gf   = blockIdx.x >> 5;    // 0..31
    const int f    = gf * 4 + wv;
    const int rb   = rg * 1024;

    // ---- per-wave resident tables ----
    const short8* wp = (const short8*)ws + (size_t)f * 512 + lane;
    short8 wfrag[4][2];
    #pragma unroll
    for (int gt = 0; gt < 4; ++gt)
        #pragma unroll
        for (int ks = 0; ks < 2; ++ks)
            wfrag[gt][ks] = wp[(gt * 2 + ks) * 64];

    // w1/b1 fp32: element k = ks*32 + quad*8 + j
    float wk[2][8], bk[2][8];
    #pragma unroll
    for (int ks = 0; ks < 2; ++ks) {
        const float4* wq = (const float4*)(w1 + f * 64 + ks * 32 + quad * 8);
        const float4* bq = (const float4*)(b1 + f * 64 + ks * 32 + quad * 8);
        *(float4*)&wk[ks][0] = wq[0]; *(float4*)&wk[ks][4] = wq[1];
        *(float4*)&bk[ks][0] = bq[0]; *(float4*)&bk[ks][4] = bq[1];
    }

    // b2/w3 fp32: element g = gt*16 + quad*4 + i
    float b2f[4][4], w3f[4][4];
    #pragma unroll
    for (int gt = 0; gt < 4; ++gt) {
        *(float4*)&b2f[gt][0] = *(const float4*)(b2 + f * 64 + gt * 16 + quad * 4);
        *(float4*)&w3f[gt][0] = *(const float4*)(w3 + f * 64 + gt * 16 + quad * 4);
    }
    const float b3f = b3[f];

    // ---- 16 chunks of 64 rows, software-pipelined x gather ----
    float xv = x[(size_t)(rb + lane) * F_SZ + f];   // chunk 0

    #pragma unroll 1
    for (int c = 0; c < 16; ++c) {
        float xvn;
        if (c < 15)
            xvn = x[(size_t)(rb + (c + 1) * 64 + lane) * F_SZ + f];

        float xf[4];
        #pragma unroll
        for (int bt = 0; bt < 4; ++bt)
            xf[bt] = __shfl(xv, bt * 16 + l15, 64);

        // h1 B-fragments: B[k=quad*8+j][n=bt*16+l15]
        short8 hfrag[4][2];
        #pragma unroll
        for (int ks = 0; ks < 2; ++ks)
            #pragma unroll
            for (int bt = 0; bt < 4; ++bt) {
                union { short8 s8; __hip_bfloat162 h2[4]; } o;
                #pragma unroll
                for (int t = 0; t < 4; ++t) {
                    float h0 = fmaxf(fmaf(xf[bt], wk[ks][2 * t],     bk[ks][2 * t]),     0.0f);
                    float h1 = fmaxf(fmaf(xf[bt], wk[ks][2 * t + 1], bk[ks][2 * t + 1]), 0.0f);
                    o.h2[t] = __float22bfloat162_rn(make_float2(h0, h1));
                }
                hfrag[bt][ks] = o.s8;
            }

        // MFMA + epilogue; D layout: g = gt*16 + quad*4 + i, n = bt*16 + l15
        float t[4] = {0.0f, 0.0f, 0.0f, 0.0f};
        #pragma unroll
        for (int gt = 0; gt < 4; ++gt)
            #pragma unroll
            for (int bt = 0; bt < 4; ++bt) {
                floatx4 acc = {b2f[gt][0], b2f[gt][1], b2f[gt][2], b2f[gt][3]};
                acc = __builtin_amdgcn_mfma_f32_16x16x32_bf16(
                    wfrag[gt][0], hfrag[bt][0], acc, 0, 0, 0);
                acc = __builtin_amdgcn_mfma_f32_16x16x32_bf16(
                    wfrag[gt][1], hfrag[bt][1], acc, 0, 0, 0);
                #pragma unroll
                for (int i = 0; i < 4; ++i)
                    t[bt] = fmaf(fmaxf(acc[i], 0.0f), w3f[gt][i], t[bt]);
            }

        // quad-reduce (row = bt*16 + l15), publish per-chunk rows
        #pragma unroll
        for (int bt = 0; bt < 4; ++bt) {
            t[bt] += __shfl_xor(t[bt], 16, 64);
            t[bt] += __shfl_xor(t[bt], 32, 64);
        }
        if (quad == 0) {
            #pragma unroll
            for (int bt = 0; bt < 4; ++bt)
                partial[wv][c * 64 + bt * 16 + l15] = t[bt] + b3f;
        }

        xv = xvn;
    }

    __syncthreads();

    // block reduce over the 4 features -> plain coalesced store (sole writer)
    #pragma unroll
    for (int k = 0; k < 4; ++k) {
        int row = k * 256 + tid;
        float p = partial[0][row] + partial[1][row]
                + partial[2][row] + partial[3][row];
        part[(size_t)gf * B_SZ + rb + row] = p;
    }
}

// ---- final: 1 row/thread, sum 32 gf-partials + bias + sigmoid ----
__global__ __launch_bounds__(256)
void nam_final(const float* __restrict__ part, const float* __restrict__ bias,
               float* __restrict__ out)
{
    int b = blockIdx.x * 256 + threadIdx.x;
    float s = bias[0];
    #pragma unroll
    for (int gf = 0; gf < 32; ++gf)
        s += part[(size_t)gf * B_SZ + b];
    float p = 1.0f / (1.0f + __expf(-s));
    ((float2*)out)[b] = make_float2(1.0f - p, p);
}

extern "C" void kernel_launch(void* const* d_in, const int* in_sizes, int n_in,
                              void* d_out, int out_size, void* d_ws, size_t ws_size,
                              hipStream_t stream)
{
    const float* x    = (const float*)d_in[0];
    const float* w1   = (const float*)d_in[1];
    const float* b1   = (const float*)d_in[2];
    const float* w2   = (const float*)d_in[3];
    const float* b2   = (const float*)d_in[4];
    const float* w3   = (const float*)d_in[5];
    const float* b3   = (const float*)d_in[6];
    const float* bias = (const float*)d_in[7];
    float* out = (float*)d_out;

    unsigned short* ws = (unsigned short*)d_ws;
    float* part = (float*)(ws + WS_PART_SHORTS);

    nam_prep<<<dim3(256), dim3(256), 0, stream>>>(w2, ws);
    nam_main<<<dim3(1024), dim3(256), 0, stream>>>(
        x, w1, b1, b2, w3, b3, ws, part);
    nam_final<<<dim3(B_SZ / 256), dim3(256), 0, stream>>>(part, bias, out);
}

// Round 16
// 125.494 us; speedup vs baseline: 1.5136x; 1.1842x over previous
//
#include <hip/hip_runtime.h>
#include <hip/hip_bf16.h>

// NAM_89739046683406: per-feature tiny MLP (B=32768, F=128, H=64)
// logit(b) = bias + sum_f [ relu(relu(x[b,f]*w1[f]+b1[f]) @ w2[f] + b2[f]) . w3[f] + b3[f] ]
// out = [1-sigmoid, sigmoid]
//
// R16: LB(256,3) restored — R13/R14/R15's regression was launch_bounds(256,4)
// forcing VGPR 76->64 -> in-loop scratch spills (WRITE 4->43.8MB, FETCH 2x).
// Keep R15's plain sole-writer stores (no atomics, no zero pass), keep the x
// prefetch, grid 2048 (rg=64, 8 chunks of 64 rows) for finer tail granularity.
// Row-sharing blocks are 64 apart (=0 mod 8) -> same XCD -> L2 x-line reuse.

#define B_SZ 32768
#define F_SZ 128
#define H_SZ 64

typedef short short8 __attribute__((ext_vector_type(8)));   // bf16 x8
typedef float floatx4 __attribute__((ext_vector_type(4)));  // fp32 x4 acc

// round-half-up bf16 pair-pack (proven form)
__device__ __forceinline__ unsigned pkbf(float lo, float hi) {
    unsigned ua = __float_as_uint(lo) + 0x8000u;
    unsigned ub = __float_as_uint(hi) + 0x8000u;
    return (ua >> 16) | (ub & 0xFFFF0000u);
}

// ws layout (bytes): [0, 1MB) w2bf fragment table; [1MB, 5MB) part[32][32768]
#define WS_PART_SHORTS 524288

// ---- prep: pack w2 -> A-fragment order (grid-strided, uniform, 256 blocks)
// fragment layout: per f, unit idx = c*64+lane (c = gt*2+ks):
//   value = w2[f][k=(c&1)*32+(lane>>4)*8+j][g=(c>>1)*16+(lane&15)], j=0..7
__global__ __launch_bounds__(256)
void nam_prep(const float* __restrict__ w2, unsigned short* __restrict__ ws)
{
    int unit = blockIdx.x * 256 + threadIdx.x;   // 0..65535
    int f    = unit >> 9;             // 0..127
    int idx  = unit & 511;
    int c    = idx >> 6;
    int lane = idx & 63;
    int g    = (c >> 1) * 16 + (lane & 15);
    int k0   = (c & 1) * 32 + (lane >> 4) * 8;
    const float* w2f = w2 + (size_t)f * 4096;
    unsigned o0 = pkbf(w2f[(k0 + 0) * 64 + g], w2f[(k0 + 1) * 64 + g]);
    unsigned o1 = pkbf(w2f[(k0 + 2) * 64 + g], w2f[(k0 + 3) * 64 + g]);
    unsigned o2 = pkbf(w2f[(k0 + 4) * 64 + g], w2f[(k0 + 5) * 64 + g]);
    unsigned o3 = pkbf(w2f[(k0 + 6) * 64 + g], w2f[(k0 + 7) * 64 + g]);
    *(uint4*)((unsigned*)ws + ((size_t)f * 512 + idx) * 4) =
        make_uint4(o0, o1, o2, o3);
}

// ---- main: block = 4 waves; wave wv owns feature f = (bx>>6)*4+wv,
//      rows [rg*512, rg*512+512), rg = bx&63. 8 chunks of 64 rows.
//      Output: part[gf][rb..rb+512) plain store (sole writer).
__global__ __launch_bounds__(256, 3)
void nam_main(const float* __restrict__ x,
              const float* __restrict__ w1, const float* __restrict__ b1,
              const float* __restrict__ b2, const float* __restrict__ w3,
              const float* __restrict__ b3,
              const unsigned short* __restrict__ ws,
              float* __restrict__ part)
{
    __shared__ float partial[4][512];    // 8KB

    const int tid  = threadIdx.x;
    const int lane = tid & 63;
    const int wv   = tid >> 6;           // 0..3
    const int l15  = lane & 15;
    const int quad = lane >> 4;
    const int rg   = blockIdx.x & 63;
    const int gf   = blockIdx.x >> 6;    // 0..31
    const int f    = gf * 4 + wv;
    const int rb   = rg * 512;

    // ---- per-wave resident tables ----
    const short8* wp = (const short8*)ws + (size_t)f * 512 + lane;
    short8 wfrag[4][2];
    #pragma unroll
    for (int gt = 0; gt < 4; ++gt)
        #pragma unroll
        for (int ks = 0; ks < 2; ++ks)
            wfrag[gt][ks] = wp[(gt * 2 + ks) * 64];

    // w1/b1 fp32: element k = ks*32 + quad*8 + j
    float wk[2][8], bk[2][8];
    #pragma unroll
    for (int ks = 0; ks < 2; ++ks) {
        const float4* wq = (const float4*)(w1 + f * 64 + ks * 32 + quad * 8);
        const float4* bq = (const float4*)(b1 + f * 64 + ks * 32 + quad * 8);
        *(float4*)&wk[ks][0] = wq[0]; *(float4*)&wk[ks][4] = wq[1];
        *(float4*)&bk[ks][0] = bq[0]; *(float4*)&bk[ks][4] = bq[1];
    }

    // b2/w3 fp32: element g = gt*16 + quad*4 + i
    float b2f[4][4], w3f[4][4];
    #pragma unroll
    for (int gt = 0; gt < 4; ++gt) {
        *(float4*)&b2f[gt][0] = *(const float4*)(b2 + f * 64 + gt * 16 + quad * 4);
        *(float4*)&w3f[gt][0] = *(const float4*)(w3 + f * 64 + gt * 16 + quad * 4);
    }
    const float b3f = b3[f];

    // ---- 8 chunks of 64 rows, software-pipelined x gather ----
    float xv = x[(size_t)(rb + lane) * F_SZ + f];   // chunk 0

    #pragma unroll 1
    for (int c = 0; c < 8; ++c) {
        float xvn;
        if (c < 7)
            xvn = x[(size_t)(rb + (c + 1) * 64 + lane) * F_SZ + f];

        float xf[4];
        #pragma unroll
        for (int bt = 0; bt < 4; ++bt)
            xf[bt] = __shfl(xv, bt * 16 + l15, 64);

        // h1 B-fragments: B[k=quad*8+j][n=bt*16+l15]
        short8 hfrag[4][2];
        #pragma unroll
        for (int ks = 0; ks < 2; ++ks)
            #pragma unroll
            for (int bt = 0; bt < 4; ++bt) {
                union { short8 s8; __hip_bfloat162 h2[4]; } o;
                #pragma unroll
                for (int t = 0; t < 4; ++t) {
                    float h0 = fmaxf(fmaf(xf[bt], wk[ks][2 * t],     bk[ks][2 * t]),     0.0f);
                    float h1 = fmaxf(fmaf(xf[bt], wk[ks][2 * t + 1], bk[ks][2 * t + 1]), 0.0f);
                    o.h2[t] = __float22bfloat162_rn(make_float2(h0, h1));
                }
                hfrag[bt][ks] = o.s8;
            }

        // MFMA + epilogue; D layout: g = gt*16 + quad*4 + i, n = bt*16 + l15
        float t[4] = {0.0f, 0.0f, 0.0f, 0.0f};
        #pragma unroll
        for (int gt = 0; gt < 4; ++gt)
            #pragma unroll
            for (int bt = 0; bt < 4; ++bt) {
                floatx4 acc = {b2f[gt][0], b2f[gt][1], b2f[gt][2], b2f[gt][3]};
                acc = __builtin_amdgcn_mfma_f32_16x16x32_bf16(
                    wfrag[gt][0], hfrag[bt][0], acc, 0, 0, 0);
                acc = __builtin_amdgcn_mfma_f32_16x16x32_bf16(
                    wfrag[gt][1], hfrag[bt][1], acc, 0, 0, 0);
                #pragma unroll
                for (int i = 0; i < 4; ++i)
                    t[bt] = fmaf(fmaxf(acc[i], 0.0f), w3f[gt][i], t[bt]);
            }

        // quad-reduce (row = bt*16 + l15), publish per-chunk rows
        #pragma unroll
        for (int bt = 0; bt < 4; ++bt) {
            t[bt] += __shfl_xor(t[bt], 16, 64);
            t[bt] += __shfl_xor(t[bt], 32, 64);
        }
        if (quad == 0) {
            #pragma unroll
            for (int bt = 0; bt < 4; ++bt)
                partial[wv][c * 64 + bt * 16 + l15] = t[bt] + b3f;
        }

        xv = xvn;
    }

    __syncthreads();

    // block reduce over the 4 features -> plain coalesced store (sole writer)
    #pragma unroll
    for (int k = 0; k < 2; ++k) {
        int row = k * 256 + tid;
        float p = partial[0][row] + partial[1][row]
                + partial[2][row] + partial[3][row];
        part[(size_t)gf * B_SZ + rb + row] = p;
    }
}

// ---- final: 1 row/thread, sum 32 gf-partials + bias + sigmoid ----
__global__ __launch_bounds__(256)
void nam_final(const float* __restrict__ part, const float* __restrict__ bias,
               float* __restrict__ out)
{
    int b = blockIdx.x * 256 + threadIdx.x;
    float s = bias[0];
    #pragma unroll
    for (int gf = 0; gf < 32; ++gf)
        s += part[(size_t)gf * B_SZ + b];
    float p = 1.0f / (1.0f + __expf(-s));
    ((float2*)out)[b] = make_float2(1.0f - p, p);
}

extern "C" void kernel_launch(void* const* d_in, const int* in_sizes, int n_in,
                              void* d_out, int out_size, void* d_ws, size_t ws_size,
                              hipStream_t stream)
{
    const float* x    = (const float*)d_in[0];
    const float* w1   = (const float*)d_in[1];
    const float* b1   = (const float*)d_in[2];
    const float* w2   = (const float*)d_in[3];
    const float* b2   = (const float*)d_in[4];
    const float* w3   = (const float*)d_in[5];
    const float* b3   = (const float*)d_in[6];
    const float* bias = (const float*)d_in[7];
    float* out = (float*)d_out;

    unsigned short* ws = (unsigned short*)d_ws;
    float* part = (float*)(ws + WS_PART_SHORTS);

    nam_prep<<<dim3(256), dim3(256), 0, stream>>>(w2, ws);
    nam_main<<<dim3(2048), dim3(256), 0, stream>>>(
        x, w1, b1, b2, w3, b3, ws, part);
    nam_final<<<dim3(B_SZ / 256), dim3(256), 0, stream>>>(part, bias, out);
}